// Round 1
// baseline (387.380 us; speedup 1.0000x reference)
//
#include <hip/hip_runtime.h>
#include <math.h>

// SmartDerivatives: out[b, a*3+dim] = (segment_sum(left * x[b,des]))^2
// Exploits the deterministic triu_indices(100,1) structure of the scatter:
// descriptor d = pair (i,j), row-major; 6 nonzeros per d: (i,0..2),(j,0..2).
// Index arrays (d_in[2..4]) are never read -> saves ~365 MB of HBM traffic.

#define N_ATOMS 100
#define D_DESC  4950      // 100*99/2
#define BATCH   1024
#define NOUT    (N_ATOMS * 3)   // 300

__device__ __forceinline__ int rowstart(int i) {
    // sum_{k<i} (99-k) = i*(199-i)/2
    return (i * (2 * N_ATOMS - 1 - i)) >> 1;
}

__global__ __launch_bounds__(256, 4)
void SmartDerivatives_kernel(const float* __restrict__ x,
                             const float* __restrict__ left,
                             float* __restrict__ out) {
    __shared__ float acc[NOUT];
    const int b   = blockIdx.x;
    const int tid = threadIdx.x;

    for (int t = tid; t < NOUT; t += 256) acc[t] = 0.0f;
    __syncthreads();

    const float* __restrict__ xb = x    + (size_t)b * D_DESC;
    const float* __restrict__ lb = left + (size_t)b * D_DESC * 6;

    // ---- j-part: stream descriptors, lane-per-d. Consecutive lanes hit
    // consecutive j -> stride-3 LDS addresses, ~no same-address conflicts.
    for (int d = tid; d < D_DESC; d += 256) {
        const float xv = xb[d];
        // invert d -> row i of triu(100,1)
        const float fr = 39601.0f - 8.0f * (float)d;   // 199^2 - 8d
        int i = (int)((199.0f - sqrtf(fr)) * 0.5f);
        while (rowstart(i + 1) <= d) ++i;   // fixup fp rounding
        while (rowstart(i) > d) --i;
        const int j = d - rowstart(i) + i + 1;

        const float* lp = lb + (size_t)d * 6;
        const float l3 = lp[3], l4 = lp[4], l5 = lp[5];
        atomicAdd(&acc[j * 3 + 0], l3 * xv);
        atomicAdd(&acc[j * 3 + 1], l4 * xv);
        atomicAdd(&acc[j * 3 + 2], l5 * xv);
    }

    // ---- i-part: row a's descriptors are contiguous [rowstart(a), +len).
    // One row per wave: register partials + shuffle reduce, 3 atomics/row.
    const int wave = tid >> 6;
    const int lane = tid & 63;
    for (int a = wave; a < N_ATOMS - 1; a += 4) {
        const int rs  = rowstart(a);
        const int len = N_ATOMS - 1 - a;
        float s0 = 0.0f, s1 = 0.0f, s2 = 0.0f;
        for (int l = lane; l < len; l += 64) {
            const int d = rs + l;
            const float xv = xb[d];
            const float* lp = lb + (size_t)d * 6;
            s0 += lp[0] * xv;
            s1 += lp[1] * xv;
            s2 += lp[2] * xv;
        }
        #pragma unroll
        for (int off = 32; off > 0; off >>= 1) {
            s0 += __shfl_down(s0, off, 64);
            s1 += __shfl_down(s1, off, 64);
            s2 += __shfl_down(s2, off, 64);
        }
        if (lane == 0) {
            atomicAdd(&acc[a * 3 + 0], s0);
            atomicAdd(&acc[a * 3 + 1], s1);
            atomicAdd(&acc[a * 3 + 2], s2);
        }
    }

    __syncthreads();

    // ---- epilogue: square, coalesced store
    float* __restrict__ ob = out + (size_t)b * NOUT;
    for (int t = tid; t < NOUT; t += 256) {
        const float v = acc[t];
        ob[t] = v * v;
    }
}

extern "C" void kernel_launch(void* const* d_in, const int* in_sizes, int n_in,
                              void* d_out, int out_size, void* d_ws, size_t ws_size,
                              hipStream_t stream) {
    const float* x    = (const float*)d_in[0];   // [BATCH, D]
    const float* left = (const float*)d_in[1];   // [BATCH*D*6]
    float* out = (float*)d_out;                  // [BATCH, 300]
    SmartDerivatives_kernel<<<BATCH, 256, 0, stream>>>(x, left, out);
}

// Round 2
// 384.012 us; speedup vs baseline: 1.0088x; 1.0088x over previous
//
#include <hip/hip_runtime.h>
#include <math.h>

// SmartDerivatives: out[b, a*3+dim] = (segment_sum(left * x[b,des]))^2
// Exploits the deterministic triu_indices(100,1) structure of the scatter:
// descriptor d = pair (i,j), row-major; 6 nonzeros per d: (i,0..2),(j,0..2).
// Index arrays (d_in[2..4]) are never read -> saves ~365 MB of HBM traffic.
//
// R2: 512 thr/block (32 waves/CU cap) + float4-vectorized pair loads in the
// j-pass to raise bytes-in-flight. R1 was latency-bound (HBM 16%, VALU 13%,
// occ 41%).

#define N_ATOMS 100
#define D_DESC  4950      // 100*99/2
#define NPAIR   (D_DESC / 2)   // 2475
#define BATCH   1024
#define NOUT    (N_ATOMS * 3)  // 300

__device__ __forceinline__ int rowstart(int i) {
    // sum_{k<i} (99-k) = i*(199-i)/2
    return (i * (2 * N_ATOMS - 1 - i)) >> 1;
}

__global__ __launch_bounds__(512, 8)
void SmartDerivatives_kernel(const float* __restrict__ x,
                             const float* __restrict__ left,
                             float* __restrict__ out) {
    __shared__ float acc[NOUT];
    const int b   = blockIdx.x;
    const int tid = threadIdx.x;

    for (int t = tid; t < NOUT; t += 512) acc[t] = 0.0f;
    __syncthreads();

    const float* __restrict__ xb = x    + (size_t)b * D_DESC;
    const float* __restrict__ lb = left + (size_t)b * D_DESC * 6;

    // ---- j-part: lane handles a PAIR of consecutive descriptors (48 B,
    // always 16-aligned) -> 3x float4 + 1x float2 loads. Consecutive lanes
    // hit consecutive j -> stride-3 LDS atomic addresses, ~no contention.
    const float4* __restrict__ lb4 = (const float4*)lb;
    const float2* __restrict__ xb2 = (const float2*)xb;
    for (int p = tid; p < NPAIR; p += 512) {
        const float4 q0 = lb4[(size_t)p * 3 + 0]; // d0: l0 l1 l2 l3
        const float4 q1 = lb4[(size_t)p * 3 + 1]; // d0: l4 l5 | d1: l0 l1
        const float4 q2 = lb4[(size_t)p * 3 + 2]; // d1: l2 l3 l4 l5
        const float2 xv = xb2[p];

        const int d0 = 2 * p;
        // invert d0 -> row i of triu(100,1)
        const float fr = 39601.0f - 8.0f * (float)d0;  // 199^2 - 8d
        int i0 = (int)((199.0f - sqrtf(fr)) * 0.5f);
        while (rowstart(i0 + 1) <= d0) ++i0;   // fixup fp rounding
        while (rowstart(i0) > d0) --i0;
        const int j0 = d0 - rowstart(i0) + i0 + 1;
        // d1 = d0+1: same row unless d0 ended row i0 (j0 == 99)
        const int j1 = (j0 < N_ATOMS - 1) ? (j0 + 1) : (i0 + 2);

        atomicAdd(&acc[j0 * 3 + 0], q0.w * xv.x);
        atomicAdd(&acc[j0 * 3 + 1], q1.x * xv.x);
        atomicAdd(&acc[j0 * 3 + 2], q1.y * xv.x);
        atomicAdd(&acc[j1 * 3 + 0], q2.y * xv.y);
        atomicAdd(&acc[j1 * 3 + 1], q2.z * xv.y);
        atomicAdd(&acc[j1 * 3 + 2], q2.w * xv.y);
    }

    // ---- i-part: row a's descriptors are contiguous [rowstart(a), +len).
    // One row per wave: register partials + shuffle reduce, 3 atomics/row.
    // Loads are scalar but hit L2 (lines fetched by j-pass; FETCH_SIZE
    // confirms no HBM re-read).
    const int wave = tid >> 6;
    const int lane = tid & 63;
    for (int a = wave; a < N_ATOMS - 1; a += 8) {
        const int rs  = rowstart(a);
        const int len = N_ATOMS - 1 - a;
        float s0 = 0.0f, s1 = 0.0f, s2 = 0.0f;
        for (int l = lane; l < len; l += 64) {
            const int d = rs + l;
            const float xv = xb[d];
            const float* lp = lb + (size_t)d * 6;
            s0 += lp[0] * xv;
            s1 += lp[1] * xv;
            s2 += lp[2] * xv;
        }
        #pragma unroll
        for (int off = 32; off > 0; off >>= 1) {
            s0 += __shfl_down(s0, off, 64);
            s1 += __shfl_down(s1, off, 64);
            s2 += __shfl_down(s2, off, 64);
        }
        if (lane == 0) {
            atomicAdd(&acc[a * 3 + 0], s0);
            atomicAdd(&acc[a * 3 + 1], s1);
            atomicAdd(&acc[a * 3 + 2], s2);
        }
    }

    __syncthreads();

    // ---- epilogue: square, coalesced store
    float* __restrict__ ob = out + (size_t)b * NOUT;
    for (int t = tid; t < NOUT; t += 512) {
        const float v = acc[t];
        ob[t] = v * v;
    }
}

extern "C" void kernel_launch(void* const* d_in, const int* in_sizes, int n_in,
                              void* d_out, int out_size, void* d_ws, size_t ws_size,
                              hipStream_t stream) {
    const float* x    = (const float*)d_in[0];   // [BATCH, D]
    const float* left = (const float*)d_in[1];   // [BATCH*D*6]
    float* out = (float*)d_out;                  // [BATCH, 300]
    SmartDerivatives_kernel<<<BATCH, 512, 0, stream>>>(x, left, out);
}